// Round 4
// baseline (1365.599 us; speedup 1.0000x reference)
//
#include <hip/hip_runtime.h>
#include <math.h>

#define HH 12
#define SS 2048
#define DM 768
#define DK 64

typedef _Float16 f16x8 __attribute__((ext_vector_type(8)));
typedef _Float16 f16x4 __attribute__((ext_vector_type(4)));
typedef float    f32x4 __attribute__((ext_vector_type(4)));

#define MFMA_F16(A, B, C) __builtin_amdgcn_mfma_f32_16x16x32_f16((A), (B), (C), 0, 0, 0)

// ---------------------------------------------------------------------------
// split_a: q,k,v fp32 [4096,768] -> hi/lo f16 planes (flat, row-major).
// Pure BW-bound; removes all split VALU from GEMM main loops.
// ---------------------------------------------------------------------------
__global__ __launch_bounds__(256) void split_a_kernel(
        const float* __restrict__ q, const float* __restrict__ k,
        const float* __restrict__ v,
        _Float16* __restrict__ Ahi, _Float16* __restrict__ Alo)
{
    const size_t PER = 786432;                     // float4 per input
    size_t f = (size_t)blockIdx.x * 256 + threadIdx.x;   // exact: 9216*256
    int z = (int)(f / PER);
    size_t loc = f - (size_t)z * PER;
    const float* src = (z == 0) ? q : (z == 1) ? k : v;
    float4 x = ((const float4*)src)[loc];
    float vv[4] = {x.x, x.y, x.z, x.w};
    f16x4 hi, lo;
    #pragma unroll
    for (int j = 0; j < 4; ++j) {
        _Float16 h = (_Float16)vv[j];
        hi[j] = h; lo[j] = (_Float16)(vv[j] - (float)h);
    }
    size_t off = (size_t)z * 3145728 + loc * 4;
    *(f16x4*)&Ahi[off] = hi;
    *(f16x4*)&Alo[off] = lo;
}

// ---------------------------------------------------------------------------
// conv_w: W[k][n] fp32 -> transposed split-f16 planes Wt{hi,lo}[n][k].
// ---------------------------------------------------------------------------
__global__ __launch_bounds__(256) void conv_w_kernel(
        const float* __restrict__ w0, const float* __restrict__ w1,
        const float* __restrict__ w2, const float* __restrict__ w3,
        _Float16* hi0, _Float16* lo0, _Float16* hi1, _Float16* lo1,
        _Float16* hi2, _Float16* lo2, _Float16* hi3, _Float16* lo3)
{
    __shared__ float T[64][68];
    const int z = blockIdx.z;
    const float* W = (z == 0) ? w0 : (z == 1) ? w1 : (z == 2) ? w2 : w3;
    _Float16* Whi  = (z == 0) ? hi0 : (z == 1) ? hi1 : (z == 2) ? hi2 : hi3;
    _Float16* Wlo  = (z == 0) ? lo0 : (z == 1) ? lo1 : (z == 2) ? lo2 : lo3;

    const int tid = threadIdx.x;
    const int k0 = blockIdx.y * 64, n0 = blockIdx.x * 64;

    #pragma unroll
    for (int i = 0; i < 4; ++i) {
        int r = (tid >> 4) + i * 16;
        int c = (tid & 15) * 4;
        *(float4*)&T[r][c] = *(const float4*)&W[(size_t)(k0 + r) * DM + n0 + c];
    }
    __syncthreads();

    const int n = tid >> 2, kq = (tid & 3) * 16;
    f16x8 ha, la, hb, lb;
    #pragma unroll
    for (int j = 0; j < 8; ++j) {
        float v = T[kq + j][n];
        _Float16 h = (_Float16)v;
        ha[j] = h; la[j] = (_Float16)(v - (float)h);
    }
    #pragma unroll
    for (int j = 0; j < 8; ++j) {
        float v = T[kq + 8 + j][n];
        _Float16 h = (_Float16)v;
        hb[j] = h; lb[j] = (_Float16)(v - (float)h);
    }
    size_t o = (size_t)(n0 + n) * DM + k0 + kq;
    *(f16x8*)&Whi[o]     = ha;
    *(f16x8*)&Whi[o + 8] = hb;
    *(f16x8*)&Wlo[o]     = la;
    *(f16x8*)&Wlo[o + 8] = lb;
}

// ---------------------------------------------------------------------------
// gemm16_qkv: fused Q/K/V projections (blockIdx.z selects), split-fp16 MFMA.
// A pre-split hi/lo planes; B pre-split transposed Wt[n][k]; 2 independent
// accumulator chains (accA: ah*bh, accB: al*bh + ah*bl) for ILP.
// z<2 : head-split [B,H,S,64] hi/lo via LDS-coalesced epilogue (Q, K)
// z==2: head-split transposed [B,H,64,S] hi/lo (V)
// ---------------------------------------------------------------------------
__global__ __launch_bounds__(256) void gemm16_qkv_kernel(
        const _Float16* __restrict__ Ahi, const _Float16* __restrict__ Alo,
        const _Float16* __restrict__ Wt,  // 6 planes: Qhi Qlo Khi Klo Vhi Vlo
        const float* __restrict__ b_q, const float* __restrict__ b_k,
        const float* __restrict__ b_v,
        _Float16* __restrict__ Qhi, _Float16* __restrict__ Qlo,
        _Float16* __restrict__ Khi, _Float16* __restrict__ Klo,
        _Float16* __restrict__ Vthi, _Float16* __restrict__ Vtlo)
{
    __shared__ _Float16 T[64][72];

    const int tid  = threadIdx.x;
    const int wave = tid >> 6, lane = tid & 63;
    const int lrow = lane & 15;
    const int lk   = (lane >> 4) * 8;
    const int grow = (lane >> 4) * 4;
    const int z    = blockIdx.z;
    const int n0   = blockIdx.x * 64;
    const int m0   = blockIdx.y * 64;
    const int mr   = m0 + wave * 16 + lrow;

    const size_t WPL = (size_t)DM * DM;
    const _Float16* Bhi = Wt + (size_t)z * 2 * WPL;
    const _Float16* Blo = Bhi + WPL;
    const float* bias = (z == 0) ? b_q : (z == 1) ? b_k : b_v;

    const _Float16* Ah = Ahi + (size_t)z * 3145728 + (size_t)mr * DM;
    const _Float16* Al = Alo + (size_t)z * 3145728 + (size_t)mr * DM;

    f32x4 accA[4], accB[4];
    #pragma unroll
    for (int nf = 0; nf < 4; ++nf) {
        accA[nf] = (f32x4){0.f, 0.f, 0.f, 0.f};
        accB[nf] = (f32x4){0.f, 0.f, 0.f, 0.f};
    }

    #pragma unroll 2
    for (int kt = 0; kt < 24; ++kt) {
        const int k0 = kt * 32 + lk;
        f16x8 ah = *(const f16x8*)&Ah[k0];
        f16x8 al = *(const f16x8*)&Al[k0];
        #pragma unroll
        for (int nf = 0; nf < 4; ++nf) {
            const size_t bo = (size_t)(n0 + nf * 16 + lrow) * DM + k0;
            f16x8 bh_ = *(const f16x8*)&Bhi[bo];
            f16x8 bl_ = *(const f16x8*)&Blo[bo];
            accA[nf] = MFMA_F16(ah, bh_, accA[nf]);
            accB[nf] = MFMA_F16(al, bh_, accB[nf]);
            accB[nf] = MFMA_F16(ah, bl_, accB[nf]);
        }
    }

    _Float16 hi16[4][4], lo16[4][4];
    #pragma unroll
    for (int nf = 0; nf < 4; ++nf) {
        float bb = bias[n0 + nf * 16 + lrow];
        #pragma unroll
        for (int r = 0; r < 4; ++r) {
            float vv = accA[nf][r] + accB[nf][r] + bb;
            _Float16 h = (_Float16)vv;
            hi16[nf][r] = h;
            lo16[nf][r] = (_Float16)(vv - (float)h);
        }
    }

    const int head = blockIdx.x;
    const int b_ = m0 >> 11, s0 = m0 & 2047;
    _Float16* ChiS = (z == 0) ? Qhi : Khi;
    _Float16* CloS = (z == 0) ? Qlo : Klo;

    #pragma unroll
    for (int p = 0; p < 2; ++p) {
        if (p) __syncthreads();
        #pragma unroll
        for (int nf = 0; nf < 4; ++nf)
            #pragma unroll
            for (int r = 0; r < 4; ++r) {
                _Float16 val = p ? lo16[nf][r] : hi16[nf][r];
                if (z < 2) T[wave * 16 + grow + r][nf * 16 + lrow] = val;
                else       T[nf * 16 + lrow][wave * 16 + grow + r] = val;
            }
        __syncthreads();
        int rr = tid >> 2, seg = (tid & 3) * 16;
        _Float16* dst;
        if (z < 2)
            dst = (p ? CloS : ChiS) +
                  ((size_t)(b_ * HH + head) * SS + s0 + rr) * DK + seg;
        else
            dst = (p ? Vtlo : Vthi) +
                  ((size_t)(b_ * HH + head) * DK + rr) * SS + s0 + seg;
        *(f16x8*)&dst[0] = *(const f16x8*)&T[rr][seg];
        *(f16x8*)&dst[8] = *(const f16x8*)&T[rr][seg + 8];
    }
}

// ---------------------------------------------------------------------------
// gemm16_o: out = ctx @ W_o + b_o, fp32 result. 32-wide N-tiles for occupancy
// (grid 24x64 = 1536 blocks = 6/CU).
// ---------------------------------------------------------------------------
__global__ __launch_bounds__(256) void gemm16_o_kernel(
        const _Float16* __restrict__ Ahi, const _Float16* __restrict__ Alo,
        const _Float16* __restrict__ Bhi, const _Float16* __restrict__ Blo,
        const float* __restrict__ bias, float* __restrict__ Cf)
{
    const int tid  = threadIdx.x;
    const int wave = tid >> 6, lane = tid & 63;
    const int lrow = lane & 15;
    const int lk   = (lane >> 4) * 8;
    const int grow = (lane >> 4) * 4;
    const int n0   = blockIdx.x * 32;
    const int m0   = blockIdx.y * 64;
    const int mr   = m0 + wave * 16 + lrow;

    const _Float16* Ah = Ahi + (size_t)mr * DM;
    const _Float16* Al = Alo + (size_t)mr * DM;

    f32x4 accA[2], accB[2];
    #pragma unroll
    for (int nf = 0; nf < 2; ++nf) {
        accA[nf] = (f32x4){0.f, 0.f, 0.f, 0.f};
        accB[nf] = (f32x4){0.f, 0.f, 0.f, 0.f};
    }

    #pragma unroll 2
    for (int kt = 0; kt < 24; ++kt) {
        const int k0 = kt * 32 + lk;
        f16x8 ah = *(const f16x8*)&Ah[k0];
        f16x8 al = *(const f16x8*)&Al[k0];
        #pragma unroll
        for (int nf = 0; nf < 2; ++nf) {
            const size_t bo = (size_t)(n0 + nf * 16 + lrow) * DM + k0;
            f16x8 bh_ = *(const f16x8*)&Bhi[bo];
            f16x8 bl_ = *(const f16x8*)&Blo[bo];
            accA[nf] = MFMA_F16(ah, bh_, accA[nf]);
            accB[nf] = MFMA_F16(al, bh_, accB[nf]);
            accB[nf] = MFMA_F16(ah, bl_, accB[nf]);
        }
    }

    #pragma unroll
    for (int nf = 0; nf < 2; ++nf) {
        float bb = bias[n0 + nf * 16 + lrow];
        #pragma unroll
        for (int r = 0; r < 4; ++r) {
            int m = m0 + wave * 16 + grow + r;
            Cf[(size_t)m * DM + n0 + nf * 16 + lrow] =
                accA[nf][r] + accB[nf][r] + bb;
        }
    }
}

// ---------------------------------------------------------------------------
// Fused attention, two-pass, split-fp16 MFMA, occupancy-restructured:
// block = 32 q rows x 2048 keys; 4 waves = 2 q-halves x 2 KEY-halves.
// Pass A: each wave streams its 1024 keys for its 16 q rows -> partial lsum;
// cross-wave LDS reduce gives exact l. Pass B: recompute s, write p = e^s/l
// (normalized, ONCE -- no RMW) to attnW, accumulate O = P@V; O reduced
// across key-half waves in LDS; ctx written as split hi/lo f16 planes.
// XCD-chunked bijective swizzle: 1536 blocks, 192/XCD = 3 bh of K/V per L2.
// ---------------------------------------------------------------------------
__global__ __launch_bounds__(256) void attn_kernel(
        const _Float16* __restrict__ Qhi, const _Float16* __restrict__ Qlo,
        const _Float16* __restrict__ Khi, const _Float16* __restrict__ Klo,
        const _Float16* __restrict__ Vthi, const _Float16* __restrict__ Vtlo,
        float* __restrict__ attnW,
        _Float16* __restrict__ Chi, _Float16* __restrict__ Clo)
{
    __shared__ float Ps[4][16][34];
    __shared__ float Ored[32][68];
    __shared__ float redL[2][2][16];

    const int tid  = threadIdx.x;
    const int wave = tid >> 6;
    const int lane = tid & 63;
    const int lrow = lane & 15;
    const int lk   = (lane >> 4) * 8;
    const int grow = (lane >> 4) * 4;
    const int qh   = wave >> 1;        // q-half
    const int kh   = wave & 1;         // key-half

    int fid = blockIdx.y * 64 + blockIdx.x;        // 0..1535
    int nid = (fid & 7) * 192 + (fid >> 3);        // bijective XCD chunking
    const int qt = nid & 63;                       // 0..63 (32-row q tiles)
    const int bh = nid >> 6;                       // 0..23
    const int q0 = qt * 32;
    const int qw0 = q0 + qh * 16;
    const int kbase = kh * 1024;

    const size_t qkbase = (size_t)bh * SS * DK;
    const size_t vbase  = (size_t)bh * DK * SS;

    f16x8 qfh[2], qfl[2];
    {
        const size_t qidx = qkbase + (size_t)(qw0 + lrow) * DK + lk;
        qfh[0] = *(const f16x8*)&Qhi[qidx];
        qfh[1] = *(const f16x8*)&Qhi[qidx + 32];
        qfl[0] = *(const f16x8*)&Qlo[qidx];
        qfl[1] = *(const f16x8*)&Qlo[qidx + 32];
    }

    // ---------------- pass A: partial row sums over this wave's 1024 keys ---
    float lsum[4] = {0.f, 0.f, 0.f, 0.f};
    #pragma unroll 2
    for (int t = 0; t < 64; ++t) {
        const size_t kidx = qkbase + (size_t)(kbase + t * 16 + lrow) * DK + lk;
        f16x8 kh0 = *(const f16x8*)&Khi[kidx];
        f16x8 kh1 = *(const f16x8*)&Khi[kidx + 32];
        f16x8 kl0 = *(const f16x8*)&Klo[kidx];
        f16x8 kl1 = *(const f16x8*)&Klo[kidx + 32];
        f32x4 cA = {0.f, 0.f, 0.f, 0.f};
        f32x4 cB = {0.f, 0.f, 0.f, 0.f};
        cA = MFMA_F16(qfh[0], kh0, cA);
        cA = MFMA_F16(qfh[1], kh1, cA);
        cA = MFMA_F16(qfl[0], kh0, cA);
        cB = MFMA_F16(qfl[1], kh1, cB);
        cB = MFMA_F16(qfh[0], kl0, cB);
        cB = MFMA_F16(qfh[1], kl1, cB);
        #pragma unroll
        for (int r = 0; r < 4; ++r)
            lsum[r] += __expf((cA[r] + cB[r]) * 0.125f);
    }
    #pragma unroll
    for (int r = 0; r < 4; ++r) {
        lsum[r] += __shfl_xor(lsum[r], 1, 64);
        lsum[r] += __shfl_xor(lsum[r], 2, 64);
        lsum[r] += __shfl_xor(lsum[r], 4, 64);
        lsum[r] += __shfl_xor(lsum[r], 8, 64);
    }
    if (lrow == 0) {
        #pragma unroll
        for (int r = 0; r < 4; ++r) redL[qh][kh][grow + r] = lsum[r];
    }
    __syncthreads();
    float rl[4];
    #pragma unroll
    for (int r = 0; r < 4; ++r)
        rl[r] = 1.0f / (redL[qh][0][grow + r] + redL[qh][1][grow + r]);

    // ---------------- pass B: normalized p write + PV ----------------------
    f32x4 Oacc[4];
    #pragma unroll
    for (int n = 0; n < 4; ++n) Oacc[n] = (f32x4){0.f, 0.f, 0.f, 0.f};

    float (*ps)[34] = Ps[wave];

    for (int kc = 0; kc < 32; ++kc) {              // 32 keys per iteration
        #pragma unroll
        for (int sub = 0; sub < 2; ++sub) {
            const int key0 = kbase + kc * 32 + sub * 16;
            const size_t kidx = qkbase + (size_t)(key0 + lrow) * DK + lk;
            f16x8 kh0 = *(const f16x8*)&Khi[kidx];
            f16x8 kh1 = *(const f16x8*)&Khi[kidx + 32];
            f16x8 kl0 = *(const f16x8*)&Klo[kidx];
            f16x8 kl1 = *(const f16x8*)&Klo[kidx + 32];
            f32x4 cA = {0.f, 0.f, 0.f, 0.f};
            f32x4 cB = {0.f, 0.f, 0.f, 0.f};
            cA = MFMA_F16(qfh[0], kh0, cA);
            cA = MFMA_F16(qfh[1], kh1, cA);
            cA = MFMA_F16(qfl[0], kh0, cA);
            cB = MFMA_F16(qfl[1], kh1, cB);
            cB = MFMA_F16(qfh[0], kl0, cB);
            cB = MFMA_F16(qfh[1], kl1, cB);
            #pragma unroll
            for (int r = 0; r < 4; ++r) {
                float p = __expf((cA[r] + cB[r]) * 0.125f) * rl[r];
                attnW[((size_t)bh * SS + qw0 + grow + r) * SS + key0 + lrow] = p;
                ps[grow + r][sub * 16 + lrow] = p * 256.0f;
            }
        }
        // wave-synchronous LDS transpose: C-layout -> A-layout
        float pf[8];
        #pragma unroll
        for (int j = 0; j < 8; ++j) pf[j] = ps[lrow][lk + j];
        f16x8 ph, pl;
        #pragma unroll
        for (int j = 0; j < 8; ++j) {
            _Float16 h = (_Float16)pf[j];
            ph[j] = h;
            pl[j] = (_Float16)(pf[j] - (float)h);
        }
        #pragma unroll
        for (int n = 0; n < 4; ++n) {
            const size_t vidx = vbase + (size_t)(n * 16 + lrow) * SS +
                                kbase + kc * 32 + lk;
            f16x8 vh = *(const f16x8*)&Vthi[vidx];
            f16x8 vl = *(const f16x8*)&Vtlo[vidx];
            Oacc[n] = MFMA_F16(ph, vh, Oacc[n]);
            Oacc[n] = MFMA_F16(pl, vh, Oacc[n]);
            Oacc[n] = MFMA_F16(ph, vl, Oacc[n]);
        }
    }

    // ---------------- O reduce across key-half waves ------------------------
    __syncthreads();
    if (kh == 0) {
        #pragma unroll
        for (int n = 0; n < 4; ++n)
            #pragma unroll
            for (int r = 0; r < 4; ++r)
                Ored[qh * 16 + grow + r][n * 16 + lrow] = Oacc[n][r];
    }
    __syncthreads();
    if (kh == 1) {
        #pragma unroll
        for (int n = 0; n < 4; ++n)
            #pragma unroll
            for (int r = 0; r < 4; ++r)
                Ored[qh * 16 + grow + r][n * 16 + lrow] += Oacc[n][r];
    }
    __syncthreads();

    // ctx as split hi/lo f16 planes [4096][768] (undo x256 P scaling)
    const int b_ = bh / HH, h_ = bh % HH;
    #pragma unroll
    for (int it = 0; it < 2; ++it) {
        int row = (tid >> 4) + it * 16;            // 0..31
        int c4  = (tid & 15) * 4;
        f16x4 hi, lo;
        #pragma unroll
        for (int j = 0; j < 4; ++j) {
            float vv = Ored[row][c4 + j] * 0.00390625f;
            _Float16 h = (_Float16)vv;
            hi[j] = h; lo[j] = (_Float16)(vv - (float)h);
        }
        size_t co = ((size_t)b_ * SS + q0 + row) * DM + h_ * DK + c4;
        *(f16x4*)&Chi[co] = hi;
        *(f16x4*)&Clo[co] = lo;
    }
}

// ---------------------------------------------------------------------------
// final copy: out <- res (fp32, 12.6 MB), pure BW-bound
// ---------------------------------------------------------------------------
__global__ __launch_bounds__(256) void copy_kernel(
        float* __restrict__ dst, const float* __restrict__ src)
{
    const size_t total4 = (size_t)2 * SS * DM / 4;
    size_t i = (size_t)blockIdx.x * 256 + threadIdx.x;
    const size_t stride = (size_t)gridDim.x * 256;
    float4* d4 = (float4*)dst;
    const float4* s4 = (const float4*)src;
    for (; i < total4; i += stride) d4[i] = s4[i];
}

extern "C" void kernel_launch(void* const* d_in, const int* in_sizes, int n_in,
                              void* d_out, int out_size, void* d_ws, size_t ws_size,
                              hipStream_t stream) {
    const float* q   = (const float*)d_in[0];
    const float* k   = (const float*)d_in[1];
    const float* v   = (const float*)d_in[2];
    const float* w_q = (const float*)d_in[3];
    const float* b_q = (const float*)d_in[4];
    const float* w_k = (const float*)d_in[5];
    const float* b_k = (const float*)d_in[6];
    const float* w_v = (const float*)d_in[7];
    const float* b_v = (const float*)d_in[8];
    const float* w_o = (const float*)d_in[9];
    const float* b_o = (const float*)d_in[10];

    float* out   = (float*)d_out;                    // [2,2048,768]
    float* attnW = out + (size_t)2 * SS * DM;        // [2,12,2048,2048]

    // ---- workspace: exactly the 50,331,648-byte footprint that passed ----
    _Float16* wsh = (_Float16*)d_ws;
    const size_t PL = (size_t)2 * HH * SS * DK;      // 3,145,728 halves / plane
    _Float16* Qhi   = wsh;
    _Float16* Qlo   = wsh + PL;
    _Float16* Khi   = wsh + 2 * PL;
    _Float16* Klo   = wsh + 3 * PL;
    _Float16* Vthi  = wsh + 4 * PL;
    _Float16* Vtlo  = wsh + 5 * PL;
    _Float16* ctxhi = wsh + 6 * PL;                  // ctx split planes fill the
    _Float16* ctxlo = wsh + 7 * PL;                  // old fp32 ctx slot exactly
    float* res = (float*)wsh;                        // final-out scratch over dead Q planes

    // ---- pre-attn scratch parked inside the attnW output region ----
    const size_t WPL = (size_t)DM * DM;              // 589,824 halves / plane
    _Float16* Wt   = (_Float16*)attnW;               // 6 planes (Q,K,V hi/lo)
    _Float16* AhiP = Wt + 6 * WPL;                   // 3 input hi planes
    _Float16* AloP = AhiP + 3 * PL;                  // 3 input lo planes
    // ---- W_o scratch parked inside `out` (consumed before final copy) ----
    _Float16* WtO_hi = (_Float16*)out;
    _Float16* WtO_lo = WtO_hi + WPL;

    dim3 blk(256);
    split_a_kernel<<<dim3(9216), blk, 0, stream>>>(q, k, v, AhiP, AloP);
    conv_w_kernel<<<dim3(12, 12, 4), blk, 0, stream>>>(
        w_q, w_k, w_v, w_o,
        Wt, Wt + WPL, Wt + 2 * WPL, Wt + 3 * WPL, Wt + 4 * WPL, Wt + 5 * WPL,
        WtO_hi, WtO_lo);

    gemm16_qkv_kernel<<<dim3(12, 64, 3), blk, 0, stream>>>(
        AhiP, AloP, Wt, b_q, b_k, b_v, Qhi, Qlo, Khi, Klo, Vthi, Vtlo);

    attn_kernel<<<dim3(64, 24), blk, 0, stream>>>(
        Qhi, Qlo, Khi, Klo, Vthi, Vtlo, attnW, ctxhi, ctxlo);

    gemm16_o_kernel<<<dim3(24, 64), blk, 0, stream>>>(
        ctxhi, ctxlo, WtO_hi, WtO_lo, b_o, res);

    copy_kernel<<<dim3(1024), blk, 0, stream>>>(out, res);
}